// Round 18
// baseline (682.296 us; speedup 1.0000x reference)
//
#include <hip/hip_runtime.h>
#include <math.h>

#define N_NODES 20000
#define E_EDGES 200000
#define M1 60000            // layer-1 node count (3*N)
#define TE 20               // edges per tile (5 waves x 4 edges); divides E exactly
#define NTILES (E_EDGES / TE)   // 10000
#define PBLK 512            // persistent blocks (2 per CU, 320 threads each)

typedef __attribute__((ext_vector_type(8))) short short8;
typedef __attribute__((ext_vector_type(4))) float f32x4;

// float -> bf16 (round-to-nearest-even), bit-level
__device__ __forceinline__ unsigned short f2bf(float f) {
    union { float f; unsigned int u; } v; v.f = f;
    unsigned int r = v.u + 0x7fffu + ((v.u >> 16) & 1u);
    return (unsigned short)(r >> 16);
}
__device__ __forceinline__ float bf2f(unsigned short u) {
    union { unsigned int u; float f; } v; v.u = ((unsigned int)u) << 16;
    return v.f;
}

// packed bf16 atomic add (2 adjacent bf16, 4B-aligned). Fire-and-forget.
__device__ __forceinline__ void atom_pk_raw(unsigned short* p, unsigned int pk) {
    asm volatile("global_atomic_pk_add_bf16 %0, %1, off" :: "v"(p), "v"(pk));
}

// ---------------------------------------------------------------------------
// GEMM: C[M,256] = X[M,K] @ W[K,256]  (fp32 compute, fp32 + bf16 outputs)
// ---------------------------------------------------------------------------
template<int K>
__global__ __launch_bounds__(256) void gemm_proj(const float* __restrict__ X,
                                                 const float* __restrict__ W,
                                                 float* __restrict__ C,
                                                 unsigned short* __restrict__ Ch) {
    __shared__ float Xs[16][K];
    const int row0 = blockIdx.x * 16;
    const int tid = threadIdx.x;
    for (int i4 = tid; i4 < 16 * K / 4; i4 += 256) {
        int r = i4 / (K / 4), kq = i4 - r * (K / 4);
        ((float4*)&Xs[r][0])[kq] = ((const float4*)(X + (size_t)(row0 + r) * K))[kq];
    }
    __syncthreads();
    const int rg = tid >> 6;
    const int j0 = (tid & 63) * 4;
    float acc[4][4];
#pragma unroll
    for (int r = 0; r < 4; ++r)
#pragma unroll
        for (int t = 0; t < 4; ++t) acc[r][t] = 0.f;
#pragma unroll 4
    for (int k = 0; k < K; ++k) {
        float4 wq = *(const float4*)(W + (size_t)k * 256 + j0);
#pragma unroll
        for (int r = 0; r < 4; ++r) {
            float xv = Xs[rg * 4 + r][k];
            acc[r][0] = fmaf(xv, wq.x, acc[r][0]);
            acc[r][1] = fmaf(xv, wq.y, acc[r][1]);
            acc[r][2] = fmaf(xv, wq.z, acc[r][2]);
            acc[r][3] = fmaf(xv, wq.w, acc[r][3]);
        }
    }
#pragma unroll
    for (int r = 0; r < 4; ++r) {
        const size_t base = (size_t)(row0 + rg * 4 + r) * 256 + j0;
        *(float4*)(C + base) = make_float4(acc[r][0], acc[r][1], acc[r][2], acc[r][3]);
        ushort4 h;
        h.x = f2bf(acc[r][0]); h.y = f2bf(acc[r][1]);
        h.z = f2bf(acc[r][2]); h.w = f2bf(acc[r][3]);
        *(ushort4*)(Ch + base) = h;
    }
}

// ---------------------------------------------------------------------------
// MFMA GEMM: C[M1,256] = A[M1,256](bf16) @ B, BT[n][k] pre-transposed bf16.
// ---------------------------------------------------------------------------
__global__ __launch_bounds__(256) void gemm_mfma(const unsigned short* __restrict__ A,
                                                 const unsigned short* __restrict__ BT,
                                                 float* __restrict__ C,
                                                 unsigned short* __restrict__ Ch) {
    const int tid = threadIdx.x;
    const int w = tid >> 6, lane = tid & 63;
    const int g = lane >> 4, t = lane & 15;
    const int rA = min(blockIdx.x * 64 + w * 16 + t, M1 - 1);
    const f32x4 z = {0.f, 0.f, 0.f, 0.f};
    f32x4 acc[16];
#pragma unroll
    for (int f = 0; f < 16; ++f) acc[f] = z;
#pragma unroll
    for (int ks = 0; ks < 8; ++ks) {
        short8 a = *(const short8*)(A + (size_t)rA * 256 + ks * 32 + g * 8);
#pragma unroll
        for (int f = 0; f < 16; ++f) {
            short8 b = *(const short8*)(BT + (size_t)(16 * f + t) * 256 + ks * 32 + g * 8);
            acc[f] = __builtin_amdgcn_mfma_f32_16x16x32_bf16(a, b, acc[f], 0, 0, 0);
        }
    }
    const int rC0 = blockIdx.x * 64 + w * 16 + 4 * g;
#pragma unroll
    for (int r = 0; r < 4; ++r) {
        const int row = rC0 + r;
        if (row < M1) {
#pragma unroll
            for (int f = 0; f < 16; ++f) {
                C[(size_t)row * 256 + 16 * f + t] = acc[f][r];
                Ch[(size_t)row * 256 + 16 * f + t] = f2bf(acc[f][r]);
            }
        }
    }
}

// ---------------------------------------------------------------------------
// Weight prep (swizzled): W[K][64] fp32 -> WT[64][Wpad] bf16, transposed,
// 16B-chunk XOR swizzle: element (r, k) stored at chunk (k>>3)^(r&mask).
// ---------------------------------------------------------------------------
__global__ void prep_swz(const float* __restrict__ W, unsigned short* __restrict__ WT,
                         int Kact, int Wpad, int mask) {
    int gid = blockIdx.x * 256 + threadIdx.x;
    if (gid >= 64 * Wpad) return;
    int r = gid / Wpad, kk = gid - r * Wpad;
    int cs = kk >> 3, pos = kk & 7;
    int k = ((cs ^ (r & mask)) << 3) + pos;
    WT[gid] = (k < Kact) ? f2bf(W[k * 64 + r]) : (unsigned short)0;
}
// Wp1[256][256] -> WpT[256 out][256 k] bf16 (unswizzled, for gemm_mfma)
__global__ void prep_wpt(const float* __restrict__ W, unsigned short* __restrict__ WT) {
    int i = blockIdx.x * 256 + threadIdx.x;
    if (i >= 256 * 256) return;
    int n = i >> 8, k = i & 255;
    WT[i] = f2bf(W[k * 256 + n]);
}

// ---------------------------------------------------------------------------
// x1b init / sigmoid / zero / final
// ---------------------------------------------------------------------------
__global__ void init_x1b(const float* __restrict__ proj0,
                         const float* __restrict__ theta,
                         const float* __restrict__ bias,
                         unsigned int* __restrict__ x1b) {
    int gid = blockIdx.x * 256 + threadIdx.x;               // over N*128
    if (gid >= N_NODES * 128) return;
    int v = gid >> 7, c2 = gid & 127;
    int c = c2 * 2;
    float lo = theta[c] * proj0[(size_t)v * 256 + c] + bias[c];
    float hi = theta[c + 1] * proj0[(size_t)v * 256 + c + 1] + bias[c + 1];
    unsigned int pk = (unsigned int)f2bf(lo) | ((unsigned int)f2bf(hi) << 16);
    x1b[(size_t)v * 128 + c2] = pk;
    x1b[(size_t)(N_NODES + v) * 128 + c2] = pk;
    x1b[(size_t)(2 * N_NODES + v) * 128 + c2] = pk;
}

__global__ void sigmoid_x1b(unsigned int* __restrict__ x1b) {
    int gid = blockIdx.x * 256 + threadIdx.x;               // over 3N*128
    if (gid >= M1 * 128) return;
    unsigned int u = x1b[gid];
    float lo = 1.f / (1.f + expf(-bf2f((unsigned short)(u & 0xffffu))));
    float hi = 1.f / (1.f + expf(-bf2f((unsigned short)(u >> 16))));
    x1b[gid] = (unsigned int)f2bf(lo) | ((unsigned int)f2bf(hi) << 16);
}

__global__ void zero_zacc(unsigned int* __restrict__ z, int n) {
    int gid = blockIdx.x * 256 + threadIdx.x;
    if (gid < n) z[gid] = 0u;
}

__global__ void final_out(const float* __restrict__ proj1,
                          const unsigned short* __restrict__ zacc,
                          const float* __restrict__ theta,
                          const float* __restrict__ bias,
                          float* __restrict__ out) {
    int gid = blockIdx.x * 256 + threadIdx.x;               // over M1*64
    if (gid >= M1 * 64) return;
    int v = gid >> 6, c = gid & 63;
    float b = 0.f;
#pragma unroll
    for (int h = 0; h < 4; ++h)
        b += theta[h * 64 + c] * proj1[(size_t)v * 256 + h * 64 + c];
    float base = 0.25f * b + bias[c];
#pragma unroll
    for (int p = 0; p < 3; ++p) {
        size_t idx = (size_t)(p * M1 + v) * 64 + c;
        out[idx] = base + bf2f(zacc[idx]);
    }
}

// ---------------------------------------------------------------------------
// Pair MLP core, ALL weights from LDS (swizzled; eW2-from-global is BANNED —
// r13-vs-r15 single-variable bisect showed it corrupts results here).
// wave_barrier between nb write and cross-lane nb read (rule-18 hardening).
// ---------------------------------------------------------------------------
__device__ __forceinline__ void pair_mlp(const short8 A0[2], const short8 A1[2],
                                         const unsigned short* sEW1,
                                         const unsigned short* sEW2,
                                         const float eb1c[4],
                                         unsigned short* nb,
                                         int g, int t, f32x4 a2[4]) {
    const f32x4 z = {0.f, 0.f, 0.f, 0.f};
    f32x4 a1[4] = {z, z, z, z};
    __builtin_amdgcn_s_setprio(1);
#pragma unroll
    for (int half = 0; half < 2; ++half) {
#pragma unroll
        for (int ks = 0; ks < 2; ++ks) {
            short8 a = half ? A1[ks] : A0[ks];
#pragma unroll
            for (int f = 0; f < 4; ++f) {
                short8 b = *(const short8*)(sEW1 + (16 * f + t) * 128 +
                                            (((half * 8 + ks * 4 + g) ^ t) << 3));
                a1[f] = __builtin_amdgcn_mfma_f32_16x16x32_bf16(a, b, a1[f], 0, 0, 0);
            }
        }
    }
    __builtin_amdgcn_s_setprio(0);
#pragma unroll
    for (int f = 0; f < 4; ++f) {
        const int col = 16 * f + t;
#pragma unroll
        for (int r = 0; r < 4; ++r) {
            const int row = 4 * g + r;
            float hv = a1[f][r] + eb1c[f];
            hv = (hv >= 0.f) ? hv : 0.2f * hv;
            const int chunk = (col >> 3) ^ (row & 7);
            nb[row * 64 + chunk * 8 + (col & 7)] = f2bf(hv);
        }
    }
    __builtin_amdgcn_wave_barrier();   // cross-lane LDS handoff: write -> read
#pragma unroll
    for (int f = 0; f < 4; ++f) a2[f] = z;
    __builtin_amdgcn_s_setprio(1);
#pragma unroll
    for (int ks = 0; ks < 2; ++ks) {
        const int chunk = (ks * 4 + g) ^ (t & 7);
        short8 a = *(const short8*)(nb + t * 64 + chunk * 8);
#pragma unroll
        for (int f = 0; f < 4; ++f) {
            short8 b = *(const short8*)(sEW2 + (16 * f + t) * 64 +
                                        ((((ks * 4 + g) ^ t) & 7) << 3));
            a2[f] = __builtin_amdgcn_mfma_f32_16x16x32_bf16(a, b, a2[f], 0, 0, 0);
        }
    }
    __builtin_amdgcn_s_setprio(0);
}

// ---------------------------------------------------------------------------
// pair + scatter. Both layers stage in zb, then full-wave pk atomics over
// contiguous segments (L0: 8x256B, L1: 2x(2x128B)).
// ---------------------------------------------------------------------------
template<int LAYER>
__device__ __forceinline__ void do_pair(int p,
                                        const short8 A0[2], const short8 A1[2],
                                        const unsigned short* sEW1,
                                        const unsigned short* sEW2,
                                        const float eb1c[4], const float eb2c[4],
                                        const float alpha[4],
                                        unsigned short* nb, unsigned short* zb,
                                        int g, int t, int lane, int vtp,
                                        unsigned short* __restrict__ accb) {
    f32x4 a2[4];
    pair_mlp(A0, A1, sEW1, sEW2, eb1c, nb, g, t, a2);
    if (LAYER == 0) {
        // stage scaled payload: value (f,r) of edge g -> zb[row=4g+r][col=16f+t]
#pragma unroll
        for (int f = 0; f < 4; ++f) {
            const int col = 16 * f + t;
#pragma unroll
            for (int r = 0; r < 4; ++r) {
                const int row = 4 * g + r;
                float val = alpha[r] * (a2[f][r] + eb2c[f]);
                const int chunk = (col >> 3) ^ (row & 7);
                zb[row * 64 + chunk * 8 + (col & 7)] = f2bf(val);
            }
        }
        __builtin_amdgcn_wave_barrier();   // cross-lane zb handoff
        int tg0 = __shfl(vtp, 0), tg1 = __shfl(vtp, 16);
        int tg2 = __shfl(vtp, 32), tg3 = __shfl(vtp, 48);
        const int tg[4] = {tg0, tg1, tg2, tg3};
        // 8 full-wave pk atomics, 256B contiguous each
#pragma unroll
        for (int e = 0; e < 4; ++e) {
            unsigned short* dst = accb + ((size_t)(p * N_NODES + tg[e])) * 256;
#pragma unroll
            for (int k = 0; k < 2; ++k) {
                const int idx = 128 * k + 2 * lane;   // col idx in [0,256)
                const int r = idx >> 6, c = idx & 63;
                const int zrow = 4 * e + r;
                const int chunk = (c >> 3) ^ (zrow & 7);
                unsigned int pk = *(const unsigned int*)(zb + zrow * 64 + chunk * 8 + (c & 7));
                atom_pk_raw(dst + idx, pk);
            }
        }
    } else {
        // head-reduce, stage u32-packed pairs with rotation layout.
        unsigned int* zbu = (unsigned int*)zb;
#pragma unroll
        for (int f = 0; f < 4; ++f) {
            float s = 0.f;
#pragma unroll
            for (int r = 0; r < 4; ++r) s += alpha[r] * (a2[f][r] + eb2c[f]);
            s *= 0.25f;
            float pv = __shfl_xor(s, 1);
            if (!(t & 1)) {
                unsigned int pk = (unsigned int)f2bf(s) | ((unsigned int)f2bf(pv) << 16);
                zbu[g * 32 + ((8 * f + (t >> 1) + 8 * g) & 31)] = pk;
            }
        }
        __builtin_amdgcn_wave_barrier();   // cross-lane zb handoff
        int tg0 = __shfl(vtp, 0), tg1 = __shfl(vtp, 16);
        int tg2 = __shfl(vtp, 32), tg3 = __shfl(vtp, 48);
        const int tg[4] = {tg0, tg1, tg2, tg3};
        // 2 full-wave pk atomics; each half-wave writes one contiguous 128B row
#pragma unroll
        for (int k = 0; k < 2; ++k) {
            const int ep = 2 * k + (lane >> 5);
            const int j = lane & 31;
            unsigned int pk = zbu[ep * 32 + ((j + 8 * ep) & 31)];
            unsigned short* dst = accb + ((size_t)(p * M1 + tg[ep])) * 64;
            atom_pk_raw(dst + 2 * j, pk);
        }
    }
}

// ---------------------------------------------------------------------------
// Fused edge kernel (MFMA, persistent, software-pipelined gather).
// 320-thread blocks: 5 waves x 4 edges = 20 edges/tile (divides E exactly,
// no tail).  LDS: weights 56KB + nb 10KB + zb 10KB = 76KB -> 2x77824 =
// 152KB < 160KiB, should co-schedule 2 blocks/CU = 10 waves/CU (r17's 80KB
// blocks packed only 1/CU: usable-LDS limit is between 144 and 160KB).
// ---------------------------------------------------------------------------
template<int LAYER>
__global__ __launch_bounds__(320) void fused_edge(const unsigned short* __restrict__ projh,
                                                  const int* __restrict__ ei,
                                                  const unsigned short* __restrict__ wimg,
                                                  const float* __restrict__ ab1,
                                                  const float* __restrict__ aW2,
                                                  const float* __restrict__ ab2,
                                                  const float* __restrict__ eb1,
                                                  const float* __restrict__ eb2,
                                                  unsigned short* __restrict__ accb) {
    __shared__ __align__(16) unsigned short sW[28672];   // aW1|eW1|eW2
    __shared__ __align__(16) unsigned short nb1[5][16 * 64];
    __shared__ __align__(16) unsigned short zb1[5][16 * 64];
    const unsigned short* sAW1 = sW;
    const unsigned short* sEW1 = sW + 16384;
    const unsigned short* sEW2 = sW + 24576;

    const int tid = threadIdx.x;
    // ---- stage weights (3584 short8, coalesced) ----
    for (int i = tid; i < 28672 / 8; i += 320)
        ((short8*)sW)[i] = ((const short8*)wimg)[i];
    __syncthreads();

    const int w = tid >> 6, lane = tid & 63;
    const int g = lane >> 4, t = lane & 15;
    const int ko = g * 8;
    const int tsub = t >> 2, head = t & 3;

    float ab1c[4], aW2c[4], eb1c[4], eb2c[4];
#pragma unroll
    for (int f = 0; f < 4; ++f) {
        ab1c[f] = ab1[16 * f + t];
        aW2c[f] = aW2[16 * f + t];
        eb1c[f] = eb1[16 * f + t];
        eb2c[f] = eb2[16 * f + t];
    }
    const float b2 = ab2[0];
    unsigned short* nb = &nb1[w][0];
    unsigned short* zb = &zb1[w][0];

    // ---- prologue: gather first tile ----
    int tile = blockIdx.x;
    short8 cD[2], cM[2], cS[2];
    int cvt0, cvt1, cvt2;
    {
        const int e0 = tile * TE + w * 4;
        const int ea = e0 + tsub, ec = e0 + g;
        const int iD = ei[ea], iM = ei[E_EDGES + ea], iS = ei[2 * E_EDGES + ea];
        cvt0 = ei[ec]; cvt1 = ei[E_EDGES + ec]; cvt2 = ei[2 * E_EDGES + ec];
        const unsigned short* pD = projh + (size_t)iD * 256 + head * 64;
        const unsigned short* pM = projh + (size_t)iM * 256 + head * 64;
        const unsigned short* pS = projh + (size_t)iS * 256 + head * 64;
#pragma unroll
        for (int ks = 0; ks < 2; ++ks) {
            cD[ks] = *(const short8*)(pD + ks * 32 + ko);
            cM[ks] = *(const short8*)(pM + ks * 32 + ko);
            cS[ks] = *(const short8*)(pS + ks * 32 + ko);
        }
    }

    for (; tile < NTILES; tile += PBLK) {
        const bool hn = (tile + PBLK) < NTILES;
        // ---- prefetch next tile's edge indices ----
        int niD = 0, niM = 0, niS = 0, nvt0 = 0, nvt1 = 0, nvt2 = 0;
        if (hn) {
            const int e0n = (tile + PBLK) * TE + w * 4;
            const int ean = e0n + tsub, ecn = e0n + g;
            niD = ei[ean]; niM = ei[E_EDGES + ean]; niS = ei[2 * E_EDGES + ean];
            nvt0 = ei[ecn]; nvt1 = ei[E_EDGES + ecn]; nvt2 = ei[2 * E_EDGES + ecn];
        }

        // ---- attention MLP: H = [d|m|s] @ aW1  (K=192, padded 256) ----
        const f32x4 z = {0.f, 0.f, 0.f, 0.f};
        f32x4 acc[4] = {z, z, z, z};
        __builtin_amdgcn_s_setprio(1);
#pragma unroll
        for (int role = 0; role < 3; ++role) {
#pragma unroll
            for (int ks = 0; ks < 2; ++ks) {
                short8 a = (role == 0) ? cD[ks] : (role == 1) ? cM[ks] : cS[ks];
#pragma unroll
                for (int f = 0; f < 4; ++f) {
                    short8 b = *(const short8*)(sAW1 + (16 * f + t) * 256 +
                                                (((role * 8 + ks * 4 + g) ^ t) << 3));
                    acc[f] = __builtin_amdgcn_mfma_f32_16x16x32_bf16(a, b, acc[f], 0, 0, 0);
                }
            }
        }
        __builtin_amdgcn_s_setprio(0);

        // ---- prefetch next tile's A-fragments (hides under pairs below) ----
        short8 nD[2], nM[2], nS[2];
        if (hn) {
            const unsigned short* pD = projh + (size_t)niD * 256 + head * 64;
            const unsigned short* pM = projh + (size_t)niM * 256 + head * 64;
            const unsigned short* pS = projh + (size_t)niS * 256 + head * 64;
#pragma unroll
            for (int ks = 0; ks < 2; ++ks) {
                nD[ks] = *(const short8*)(pD + ks * 32 + ko);
                nM[ks] = *(const short8*)(pM + ks * 32 + ko);
                nS[ks] = *(const short8*)(pS + ks * 32 + ko);
            }
        }

        // ---- score epilogue: relu, @aW2, allreduce, +ab2, leaky, softmax ----
        float alpha[4];
        {
            float p_[4];
#pragma unroll
            for (int r = 0; r < 4; ++r) {
                float s = 0.f;
#pragma unroll
                for (int f = 0; f < 4; ++f) {
                    float hv = fmaxf(acc[f][r] + ab1c[f], 0.f);
                    s = fmaf(hv, aW2c[f], s);
                }
                p_[r] = s;
            }
#pragma unroll
            for (int off = 1; off < 16; off <<= 1) {
#pragma unroll
                for (int r = 0; r < 4; ++r) p_[r] += __shfl_xor(p_[r], off);
            }
            float sc[4];
#pragma unroll
            for (int r = 0; r < 4; ++r) {
                float v = p_[r] + b2;
                sc[r] = (v >= 0.f) ? v : 0.2f * v;
            }
            float mx = fmaxf(fmaxf(sc[0], sc[1]), fmaxf(sc[2], sc[3]));
            float ex[4], sum = 0.f;
#pragma unroll
            for (int r = 0; r < 4; ++r) { ex[r] = expf(sc[r] - mx); sum += ex[r]; }
            float inv = 1.f / sum;
#pragma unroll
            for (int r = 0; r < 4; ++r) alpha[r] = ex[r] * inv;
        }

        // ---- 3 pair MLPs + scatter (p0=(m,s)->d, p1=(d,s)->m, p2=(d,m)->s) ----
        do_pair<LAYER>(0, cM, cS, sEW1, sEW2, eb1c, eb2c, alpha, nb, zb, g, t, lane, cvt0, accb);
        do_pair<LAYER>(1, cD, cS, sEW1, sEW2, eb1c, eb2c, alpha, nb, zb, g, t, lane, cvt1, accb);
        do_pair<LAYER>(2, cD, cM, sEW1, sEW2, eb1c, eb2c, alpha, nb, zb, g, t, lane, cvt2, accb);

        // ---- rotate pipeline ----
        if (hn) {
#pragma unroll
            for (int ks = 0; ks < 2; ++ks) { cD[ks] = nD[ks]; cM[ks] = nM[ks]; cS[ks] = nS[ks]; }
            cvt0 = nvt0; cvt1 = nvt1; cvt2 = nvt2;
        }
    }
}

// ---------------------------------------------------------------------------
extern "C" void kernel_launch(void* const* d_in, const int* in_sizes, int n_in,
                              void* d_out, int out_size, void* d_ws, size_t ws_size,
                              hipStream_t stream) {
    (void)in_sizes; (void)n_in; (void)out_size; (void)ws_size;
    const float* x0       = (const float*)d_in[0];
    const int* ei         = (const int*)d_in[1];
    const float* p0_Wp    = (const float*)d_in[2];
    const float* p0_aW1   = (const float*)d_in[3];
    const float* p0_ab1   = (const float*)d_in[4];
    const float* p0_aW2   = (const float*)d_in[5];
    const float* p0_ab2   = (const float*)d_in[6];
    const float* p0_eW1   = (const float*)d_in[7];
    const float* p0_eb1   = (const float*)d_in[8];
    const float* p0_eW2   = (const float*)d_in[9];
    const float* p0_eb2   = (const float*)d_in[10];
    const float* p0_theta = (const float*)d_in[11];
    const float* p0_bias  = (const float*)d_in[12];
    const float* p1_Wp    = (const float*)d_in[13];
    const float* p1_aW1   = (const float*)d_in[14];
    const float* p1_ab1   = (const float*)d_in[15];
    const float* p1_aW2   = (const float*)d_in[16];
    const float* p1_ab2   = (const float*)d_in[17];
    const float* p1_eW1   = (const float*)d_in[18];
    const float* p1_eb1   = (const float*)d_in[19];
    const float* p1_eW2   = (const float*)d_in[20];
    const float* p1_eb2   = (const float*)d_in[21];
    const float* p1_theta = (const float*)d_in[22];
    const float* p1_bias  = (const float*)d_in[23];

    // Workspace (floats; total ~36,541,440 f = 146.17 MB <= proven 146.56):
    //  [0, 15.36M):          proj1 fp32 (layer1); during layer0: proj0 fp32
    //                        [0,5.12M) + projh0 bf16 [5.12M,7.68M)
    //  [15.36M, 23.04M):     x1b  bf16 accumulator (3N x 256)
    //  [23.04M, 30.72M):     projh1 bf16 (3N x 256)
    //  [30.72M, 36.48M):     zacc bf16 accumulator (3*M1 x 64)
    //  [36.48M, ...):        swizzled bf16 weight images (2 x 28672) + WpT1 (65536)
    float* ws = (float*)d_ws;
    float* proj0 = ws;
    unsigned short* projh0 = (unsigned short*)(ws + 5120000);
    float* proj1 = ws;
    unsigned short* x1b    = (unsigned short*)(ws + 15360000);
    unsigned short* projh1 = (unsigned short*)(ws + 23040000);
    unsigned short* zacc   = (unsigned short*)(ws + 30720000);
    unsigned short* wt     = (unsigned short*)(ws + 36480000);
    unsigned short* wimg0 = wt;              // [aW1 16384 | eW1 8192 | eW2 4096]
    unsigned short* wimg1 = wt + 28672;
    unsigned short* wpT1  = wt + 57344;      // Wp1^T 256x256
    float* out = (float*)d_out;

    // ---- weight prep (swizzled bf16 transposes) ----
    prep_swz<<<(64 * 256 + 255) / 256, 256, 0, stream>>>(p0_aW1, wimg0,         192, 256, 15);
    prep_swz<<<(64 * 128 + 255) / 256, 256, 0, stream>>>(p0_eW1, wimg0 + 16384, 128, 128, 15);
    prep_swz<<<(64 * 64 + 255) / 256, 256, 0, stream>>>(p0_eW2, wimg0 + 24576,  64,  64,  7);
    prep_swz<<<(64 * 256 + 255) / 256, 256, 0, stream>>>(p1_aW1, wimg1,         192, 256, 15);
    prep_swz<<<(64 * 128 + 255) / 256, 256, 0, stream>>>(p1_eW1, wimg1 + 16384, 128, 128, 15);
    prep_swz<<<(64 * 64 + 255) / 256, 256, 0, stream>>>(p1_eW2, wimg1 + 24576,  64,  64,  7);
    prep_wpt<<<(256 * 256 + 255) / 256, 256, 0, stream>>>(p1_Wp, wpT1);

    // ---- layer 0 ----
    gemm_proj<64><<<N_NODES / 16, 256, 0, stream>>>(x0, p0_Wp, proj0, projh0);
    init_x1b<<<(N_NODES * 128 + 255) / 256, 256, 0, stream>>>(proj0, p0_theta, p0_bias,
                                                              (unsigned int*)x1b);
    fused_edge<0><<<PBLK, 320, 0, stream>>>(projh0, ei, wimg0, p0_ab1, p0_aW2, p0_ab2,
                                            p0_eb1, p0_eb2, x1b);
    sigmoid_x1b<<<(M1 * 128 + 255) / 256, 256, 0, stream>>>((unsigned int*)x1b);

    // ---- layer 1 ----
    gemm_mfma<<<(M1 + 63) / 64, 256, 0, stream>>>(x1b, wpT1, proj1, projh1);
    zero_zacc<<<(3 * M1 * 32 + 255) / 256, 256, 0, stream>>>((unsigned int*)zacc,
                                                             3 * M1 * 32);
    fused_edge<1><<<PBLK, 320, 0, stream>>>(projh1, ei, wimg1, p1_ab1, p1_aW2, p1_ab2,
                                            p1_eb1, p1_eb2, zacc);
    final_out<<<(M1 * 64 + 255) / 256, 256, 0, stream>>>(proj1, zacc, p1_theta,
                                                         p1_bias, out);
}

// Round 19
// 679.574 us; speedup vs baseline: 1.0040x; 1.0040x over previous
//
#include <hip/hip_runtime.h>
#include <math.h>

#define N_NODES 20000
#define E_EDGES 200000
#define M1 60000            // layer-1 node count (3*N)
#define TE 20               // edges per tile (5 waves x 4 edges); divides E exactly
#define NTILES (E_EDGES / TE)   // 10000
#define PBLK 512            // persistent blocks (2 per CU, 320 threads each)

typedef __attribute__((ext_vector_type(8))) short short8;
typedef __attribute__((ext_vector_type(4))) float f32x4;

// float -> bf16 (round-to-nearest-even), bit-level
__device__ __forceinline__ unsigned short f2bf(float f) {
    union { float f; unsigned int u; } v; v.f = f;
    unsigned int r = v.u + 0x7fffu + ((v.u >> 16) & 1u);
    return (unsigned short)(r >> 16);
}
__device__ __forceinline__ float bf2f(unsigned short u) {
    union { unsigned int u; float f; } v; v.u = ((unsigned int)u) << 16;
    return v.f;
}

// packed bf16 atomic add (2 adjacent bf16, 4B-aligned). Fire-and-forget.
__device__ __forceinline__ void atom_pk_raw(unsigned short* p, unsigned int pk) {
    asm volatile("global_atomic_pk_add_bf16 %0, %1, off" :: "v"(p), "v"(pk));
}

// ---------------------------------------------------------------------------
// GEMM: C[M,256] = X[M,K] @ W[K,256]  (fp32 compute, fp32 + bf16 outputs)
// ---------------------------------------------------------------------------
template<int K>
__global__ __launch_bounds__(256) void gemm_proj(const float* __restrict__ X,
                                                 const float* __restrict__ W,
                                                 float* __restrict__ C,
                                                 unsigned short* __restrict__ Ch) {
    __shared__ float Xs[16][K];
    const int row0 = blockIdx.x * 16;
    const int tid = threadIdx.x;
    for (int i4 = tid; i4 < 16 * K / 4; i4 += 256) {
        int r = i4 / (K / 4), kq = i4 - r * (K / 4);
        ((float4*)&Xs[r][0])[kq] = ((const float4*)(X + (size_t)(row0 + r) * K))[kq];
    }
    __syncthreads();
    const int rg = tid >> 6;
    const int j0 = (tid & 63) * 4;
    float acc[4][4];
#pragma unroll
    for (int r = 0; r < 4; ++r)
#pragma unroll
        for (int t = 0; t < 4; ++t) acc[r][t] = 0.f;
#pragma unroll 4
    for (int k = 0; k < K; ++k) {
        float4 wq = *(const float4*)(W + (size_t)k * 256 + j0);
#pragma unroll
        for (int r = 0; r < 4; ++r) {
            float xv = Xs[rg * 4 + r][k];
            acc[r][0] = fmaf(xv, wq.x, acc[r][0]);
            acc[r][1] = fmaf(xv, wq.y, acc[r][1]);
            acc[r][2] = fmaf(xv, wq.z, acc[r][2]);
            acc[r][3] = fmaf(xv, wq.w, acc[r][3]);
        }
    }
#pragma unroll
    for (int r = 0; r < 4; ++r) {
        const size_t base = (size_t)(row0 + rg * 4 + r) * 256 + j0;
        *(float4*)(C + base) = make_float4(acc[r][0], acc[r][1], acc[r][2], acc[r][3]);
        ushort4 h;
        h.x = f2bf(acc[r][0]); h.y = f2bf(acc[r][1]);
        h.z = f2bf(acc[r][2]); h.w = f2bf(acc[r][3]);
        *(ushort4*)(Ch + base) = h;
    }
}

// ---------------------------------------------------------------------------
// MFMA GEMM: C[M1,256] = A[M1,256](bf16) @ B, BT[n][k] pre-transposed bf16.
// ---------------------------------------------------------------------------
__global__ __launch_bounds__(256) void gemm_mfma(const unsigned short* __restrict__ A,
                                                 const unsigned short* __restrict__ BT,
                                                 float* __restrict__ C,
                                                 unsigned short* __restrict__ Ch) {
    const int tid = threadIdx.x;
    const int w = tid >> 6, lane = tid & 63;
    const int g = lane >> 4, t = lane & 15;
    const int rA = min(blockIdx.x * 64 + w * 16 + t, M1 - 1);
    const f32x4 z = {0.f, 0.f, 0.f, 0.f};
    f32x4 acc[16];
#pragma unroll
    for (int f = 0; f < 16; ++f) acc[f] = z;
#pragma unroll
    for (int ks = 0; ks < 8; ++ks) {
        short8 a = *(const short8*)(A + (size_t)rA * 256 + ks * 32 + g * 8);
#pragma unroll
        for (int f = 0; f < 16; ++f) {
            short8 b = *(const short8*)(BT + (size_t)(16 * f + t) * 256 + ks * 32 + g * 8);
            acc[f] = __builtin_amdgcn_mfma_f32_16x16x32_bf16(a, b, acc[f], 0, 0, 0);
        }
    }
    const int rC0 = blockIdx.x * 64 + w * 16 + 4 * g;
#pragma unroll
    for (int r = 0; r < 4; ++r) {
        const int row = rC0 + r;
        if (row < M1) {
#pragma unroll
            for (int f = 0; f < 16; ++f) {
                C[(size_t)row * 256 + 16 * f + t] = acc[f][r];
                Ch[(size_t)row * 256 + 16 * f + t] = f2bf(acc[f][r]);
            }
        }
    }
}

// ---------------------------------------------------------------------------
// Weight prep (swizzled): W[K][64] fp32 -> WT[64][Wpad] bf16, transposed,
// 16B-chunk XOR swizzle: element (r, k) stored at chunk (k>>3)^(r&mask).
// For Wpad=192 with mask=7 the XOR stays within each 8-chunk group (bijective).
// ---------------------------------------------------------------------------
__global__ void prep_swz(const float* __restrict__ W, unsigned short* __restrict__ WT,
                         int Kact, int Wpad, int mask) {
    int gid = blockIdx.x * 256 + threadIdx.x;
    if (gid >= 64 * Wpad) return;
    int r = gid / Wpad, kk = gid - r * Wpad;
    int cs = kk >> 3, pos = kk & 7;
    int k = ((cs ^ (r & mask)) << 3) + pos;
    WT[gid] = (k < Kact) ? f2bf(W[k * 64 + r]) : (unsigned short)0;
}
// Wp1[256][256] -> WpT[256 out][256 k] bf16 (unswizzled, for gemm_mfma)
__global__ void prep_wpt(const float* __restrict__ W, unsigned short* __restrict__ WT) {
    int i = blockIdx.x * 256 + threadIdx.x;
    if (i >= 256 * 256) return;
    int n = i >> 8, k = i & 255;
    WT[i] = f2bf(W[k * 256 + n]);
}

// ---------------------------------------------------------------------------
// x1b init / sigmoid / zero / final
// ---------------------------------------------------------------------------
__global__ void init_x1b(const float* __restrict__ proj0,
                         const float* __restrict__ theta,
                         const float* __restrict__ bias,
                         unsigned int* __restrict__ x1b) {
    int gid = blockIdx.x * 256 + threadIdx.x;               // over N*128
    if (gid >= N_NODES * 128) return;
    int v = gid >> 7, c2 = gid & 127;
    int c = c2 * 2;
    float lo = theta[c] * proj0[(size_t)v * 256 + c] + bias[c];
    float hi = theta[c + 1] * proj0[(size_t)v * 256 + c + 1] + bias[c + 1];
    unsigned int pk = (unsigned int)f2bf(lo) | ((unsigned int)f2bf(hi) << 16);
    x1b[(size_t)v * 128 + c2] = pk;
    x1b[(size_t)(N_NODES + v) * 128 + c2] = pk;
    x1b[(size_t)(2 * N_NODES + v) * 128 + c2] = pk;
}

__global__ void sigmoid_x1b(unsigned int* __restrict__ x1b) {
    int gid = blockIdx.x * 256 + threadIdx.x;               // over 3N*128
    if (gid >= M1 * 128) return;
    unsigned int u = x1b[gid];
    float lo = 1.f / (1.f + expf(-bf2f((unsigned short)(u & 0xffffu))));
    float hi = 1.f / (1.f + expf(-bf2f((unsigned short)(u >> 16))));
    x1b[gid] = (unsigned int)f2bf(lo) | ((unsigned int)f2bf(hi) << 16);
}

__global__ void zero_zacc(unsigned int* __restrict__ z, int n) {
    int gid = blockIdx.x * 256 + threadIdx.x;
    if (gid < n) z[gid] = 0u;
}

__global__ void final_out(const float* __restrict__ proj1,
                          const unsigned short* __restrict__ zacc,
                          const float* __restrict__ theta,
                          const float* __restrict__ bias,
                          float* __restrict__ out) {
    int gid = blockIdx.x * 256 + threadIdx.x;               // over M1*64
    if (gid >= M1 * 64) return;
    int v = gid >> 6, c = gid & 63;
    float b = 0.f;
#pragma unroll
    for (int h = 0; h < 4; ++h)
        b += theta[h * 64 + c] * proj1[(size_t)v * 256 + h * 64 + c];
    float base = 0.25f * b + bias[c];
#pragma unroll
    for (int p = 0; p < 3; ++p) {
        size_t idx = (size_t)(p * M1 + v) * 64 + c;
        out[idx] = base + bf2f(zacc[idx]);
    }
}

// ---------------------------------------------------------------------------
// Pair MLP core, ALL weights from LDS (swizzled; eW2-from-global is BANNED —
// r13-vs-r15 single-variable bisect showed it corrupts results here).
// wave_barrier between nb write and cross-lane nb read (rule-18 hardening).
// ---------------------------------------------------------------------------
__device__ __forceinline__ void pair_mlp(const short8 A0[2], const short8 A1[2],
                                         const unsigned short* sEW1,
                                         const unsigned short* sEW2,
                                         const float eb1c[4],
                                         unsigned short* nb,
                                         int g, int t, f32x4 a2[4]) {
    const f32x4 z = {0.f, 0.f, 0.f, 0.f};
    f32x4 a1[4] = {z, z, z, z};
    __builtin_amdgcn_s_setprio(1);
#pragma unroll
    for (int half = 0; half < 2; ++half) {
#pragma unroll
        for (int ks = 0; ks < 2; ++ks) {
            short8 a = half ? A1[ks] : A0[ks];
#pragma unroll
            for (int f = 0; f < 4; ++f) {
                short8 b = *(const short8*)(sEW1 + (16 * f + t) * 128 +
                                            (((half * 8 + ks * 4 + g) ^ t) << 3));
                a1[f] = __builtin_amdgcn_mfma_f32_16x16x32_bf16(a, b, a1[f], 0, 0, 0);
            }
        }
    }
    __builtin_amdgcn_s_setprio(0);
#pragma unroll
    for (int f = 0; f < 4; ++f) {
        const int col = 16 * f + t;
#pragma unroll
        for (int r = 0; r < 4; ++r) {
            const int row = 4 * g + r;
            float hv = a1[f][r] + eb1c[f];
            hv = (hv >= 0.f) ? hv : 0.2f * hv;
            const int chunk = (col >> 3) ^ (row & 7);
            nb[row * 64 + chunk * 8 + (col & 7)] = f2bf(hv);
        }
    }
    __builtin_amdgcn_wave_barrier();   // cross-lane LDS handoff: write -> read
#pragma unroll
    for (int f = 0; f < 4; ++f) a2[f] = z;
    __builtin_amdgcn_s_setprio(1);
#pragma unroll
    for (int ks = 0; ks < 2; ++ks) {
        const int chunk = (ks * 4 + g) ^ (t & 7);
        short8 a = *(const short8*)(nb + t * 64 + chunk * 8);
#pragma unroll
        for (int f = 0; f < 4; ++f) {
            short8 b = *(const short8*)(sEW2 + (16 * f + t) * 64 +
                                        ((((ks * 4 + g) ^ t) & 7) << 3));
            a2[f] = __builtin_amdgcn_mfma_f32_16x16x32_bf16(a, b, a2[f], 0, 0, 0);
        }
    }
    __builtin_amdgcn_s_setprio(0);
}

// ---------------------------------------------------------------------------
// pair + scatter. Both layers stage in zb, then full-wave pk atomics over
// contiguous segments (L0: 8x256B, L1: 2x(2x128B)).
// ---------------------------------------------------------------------------
template<int LAYER>
__device__ __forceinline__ void do_pair(int p,
                                        const short8 A0[2], const short8 A1[2],
                                        const unsigned short* sEW1,
                                        const unsigned short* sEW2,
                                        const float eb1c[4], const float eb2c[4],
                                        const float alpha[4],
                                        unsigned short* nb, unsigned short* zb,
                                        int g, int t, int lane, int vtp,
                                        unsigned short* __restrict__ accb) {
    f32x4 a2[4];
    pair_mlp(A0, A1, sEW1, sEW2, eb1c, nb, g, t, a2);
    if (LAYER == 0) {
        // stage scaled payload: value (f,r) of edge g -> zb[row=4g+r][col=16f+t]
#pragma unroll
        for (int f = 0; f < 4; ++f) {
            const int col = 16 * f + t;
#pragma unroll
            for (int r = 0; r < 4; ++r) {
                const int row = 4 * g + r;
                float val = alpha[r] * (a2[f][r] + eb2c[f]);
                const int chunk = (col >> 3) ^ (row & 7);
                zb[row * 64 + chunk * 8 + (col & 7)] = f2bf(val);
            }
        }
        __builtin_amdgcn_wave_barrier();   // cross-lane zb handoff
        int tg0 = __shfl(vtp, 0), tg1 = __shfl(vtp, 16);
        int tg2 = __shfl(vtp, 32), tg3 = __shfl(vtp, 48);
        const int tg[4] = {tg0, tg1, tg2, tg3};
        // 8 full-wave pk atomics, 256B contiguous each
#pragma unroll
        for (int e = 0; e < 4; ++e) {
            unsigned short* dst = accb + ((size_t)(p * N_NODES + tg[e])) * 256;
#pragma unroll
            for (int k = 0; k < 2; ++k) {
                const int idx = 128 * k + 2 * lane;   // col idx in [0,256)
                const int r = idx >> 6, c = idx & 63;
                const int zrow = 4 * e + r;
                const int chunk = (c >> 3) ^ (zrow & 7);
                unsigned int pk = *(const unsigned int*)(zb + zrow * 64 + chunk * 8 + (c & 7));
                atom_pk_raw(dst + idx, pk);
            }
        }
    } else {
        // head-reduce, stage u32-packed pairs with rotation layout.
        unsigned int* zbu = (unsigned int*)zb;
#pragma unroll
        for (int f = 0; f < 4; ++f) {
            float s = 0.f;
#pragma unroll
            for (int r = 0; r < 4; ++r) s += alpha[r] * (a2[f][r] + eb2c[f]);
            s *= 0.25f;
            float pv = __shfl_xor(s, 1);
            if (!(t & 1)) {
                unsigned int pk = (unsigned int)f2bf(s) | ((unsigned int)f2bf(pv) << 16);
                zbu[g * 32 + ((8 * f + (t >> 1) + 8 * g) & 31)] = pk;
            }
        }
        __builtin_amdgcn_wave_barrier();   // cross-lane zb handoff
        int tg0 = __shfl(vtp, 0), tg1 = __shfl(vtp, 16);
        int tg2 = __shfl(vtp, 32), tg3 = __shfl(vtp, 48);
        const int tg[4] = {tg0, tg1, tg2, tg3};
        // 2 full-wave pk atomics; each half-wave writes one contiguous 128B row
#pragma unroll
        for (int k = 0; k < 2; ++k) {
            const int ep = 2 * k + (lane >> 5);
            const int j = lane & 31;
            unsigned int pk = zbu[ep * 32 + ((j + 8 * ep) & 31)];
            unsigned short* dst = accb + ((size_t)(p * M1 + tg[ep])) * 64;
            atom_pk_raw(dst + 2 * j, pk);
        }
    }
}

// ---------------------------------------------------------------------------
// Fused edge kernel (MFMA, persistent, software-pipelined gather).
// 320-thread blocks: 5 waves x 4 edges = 20 edges/tile (divides E exactly).
// aW1 staged at TRUE 192 width (24KB, mask-7 swizzle; the 256-pad was dead
// zeros -> arithmetic identical).  LDS: 48KB weights + 10KB nb + 10KB zb
// = 69632 B -> rounds to 73728 (8KB granule), 2x73728 = 147456 B which is
// the r16-PROVEN 2-blocks/CU packing -> 10 waves/CU (was 5 in r18).
// ---------------------------------------------------------------------------
template<int LAYER>
__global__ __launch_bounds__(320) void fused_edge(const unsigned short* __restrict__ projh,
                                                  const int* __restrict__ ei,
                                                  const unsigned short* __restrict__ wimg,
                                                  const float* __restrict__ ab1,
                                                  const float* __restrict__ aW2,
                                                  const float* __restrict__ ab2,
                                                  const float* __restrict__ eb1,
                                                  const float* __restrict__ eb2,
                                                  unsigned short* __restrict__ accb) {
    __shared__ __align__(16) unsigned short sW[24576];   // aW1 12288 | eW1 8192 | eW2 4096
    __shared__ __align__(16) unsigned short nb1[5][16 * 64];
    __shared__ __align__(16) unsigned short zb1[5][16 * 64];
    const unsigned short* sAW1 = sW;
    const unsigned short* sEW1 = sW + 12288;
    const unsigned short* sEW2 = sW + 20480;

    const int tid = threadIdx.x;
    // ---- stage weights (3072 short8, coalesced) ----
    for (int i = tid; i < 24576 / 8; i += 320)
        ((short8*)sW)[i] = ((const short8*)wimg)[i];
    __syncthreads();

    const int w = tid >> 6, lane = tid & 63;
    const int g = lane >> 4, t = lane & 15;
    const int ko = g * 8;
    const int tsub = t >> 2, head = t & 3;

    float ab1c[4], aW2c[4], eb1c[4], eb2c[4];
#pragma unroll
    for (int f = 0; f < 4; ++f) {
        ab1c[f] = ab1[16 * f + t];
        aW2c[f] = aW2[16 * f + t];
        eb1c[f] = eb1[16 * f + t];
        eb2c[f] = eb2[16 * f + t];
    }
    const float b2 = ab2[0];
    unsigned short* nb = &nb1[w][0];
    unsigned short* zb = &zb1[w][0];

    // ---- prologue: gather first tile ----
    int tile = blockIdx.x;
    short8 cD[2], cM[2], cS[2];
    int cvt0, cvt1, cvt2;
    {
        const int e0 = tile * TE + w * 4;
        const int ea = e0 + tsub, ec = e0 + g;
        const int iD = ei[ea], iM = ei[E_EDGES + ea], iS = ei[2 * E_EDGES + ea];
        cvt0 = ei[ec]; cvt1 = ei[E_EDGES + ec]; cvt2 = ei[2 * E_EDGES + ec];
        const unsigned short* pD = projh + (size_t)iD * 256 + head * 64;
        const unsigned short* pM = projh + (size_t)iM * 256 + head * 64;
        const unsigned short* pS = projh + (size_t)iS * 256 + head * 64;
#pragma unroll
        for (int ks = 0; ks < 2; ++ks) {
            cD[ks] = *(const short8*)(pD + ks * 32 + ko);
            cM[ks] = *(const short8*)(pM + ks * 32 + ko);
            cS[ks] = *(const short8*)(pS + ks * 32 + ko);
        }
    }

    for (; tile < NTILES; tile += PBLK) {
        const bool hn = (tile + PBLK) < NTILES;
        // ---- prefetch next tile's edge indices ----
        int niD = 0, niM = 0, niS = 0, nvt0 = 0, nvt1 = 0, nvt2 = 0;
        if (hn) {
            const int e0n = (tile + PBLK) * TE + w * 4;
            const int ean = e0n + tsub, ecn = e0n + g;
            niD = ei[ean]; niM = ei[E_EDGES + ean]; niS = ei[2 * E_EDGES + ean];
            nvt0 = ei[ecn]; nvt1 = ei[E_EDGES + ecn]; nvt2 = ei[2 * E_EDGES + ecn];
        }

        // ---- attention MLP: H = [d|m|s] @ aW1  (K=192, compact layout) ----
        const f32x4 z = {0.f, 0.f, 0.f, 0.f};
        f32x4 acc[4] = {z, z, z, z};
        __builtin_amdgcn_s_setprio(1);
#pragma unroll
        for (int role = 0; role < 3; ++role) {
#pragma unroll
            for (int ks = 0; ks < 2; ++ks) {
                short8 a = (role == 0) ? cD[ks] : (role == 1) ? cM[ks] : cS[ks];
#pragma unroll
                for (int f = 0; f < 4; ++f) {
                    short8 b = *(const short8*)(sAW1 + (16 * f + t) * 192 +
                                                (((role * 8 + ks * 4 + g) ^ (t & 7)) << 3));
                    acc[f] = __builtin_amdgcn_mfma_f32_16x16x32_bf16(a, b, acc[f], 0, 0, 0);
                }
            }
        }
        __builtin_amdgcn_s_setprio(0);

        // ---- prefetch next tile's A-fragments (hides under pairs below) ----
        short8 nD[2], nM[2], nS[2];
        if (hn) {
            const unsigned short* pD = projh + (size_t)niD * 256 + head * 64;
            const unsigned short* pM = projh + (size_t)niM * 256 + head * 64;
            const unsigned short* pS = projh + (size_t)niS * 256 + head * 64;
#pragma unroll
            for (int ks = 0; ks < 2; ++ks) {
                nD[ks] = *(const short8*)(pD + ks * 32 + ko);
                nM[ks] = *(const short8*)(pM + ks * 32 + ko);
                nS[ks] = *(const short8*)(pS + ks * 32 + ko);
            }
        }

        // ---- score epilogue: relu, @aW2, allreduce, +ab2, leaky, softmax ----
        float alpha[4];
        {
            float p_[4];
#pragma unroll
            for (int r = 0; r < 4; ++r) {
                float s = 0.f;
#pragma unroll
                for (int f = 0; f < 4; ++f) {
                    float hv = fmaxf(acc[f][r] + ab1c[f], 0.f);
                    s = fmaf(hv, aW2c[f], s);
                }
                p_[r] = s;
            }
#pragma unroll
            for (int off = 1; off < 16; off <<= 1) {
#pragma unroll
                for (int r = 0; r < 4; ++r) p_[r] += __shfl_xor(p_[r], off);
            }
            float sc[4];
#pragma unroll
            for (int r = 0; r < 4; ++r) {
                float v = p_[r] + b2;
                sc[r] = (v >= 0.f) ? v : 0.2f * v;
            }
            float mx = fmaxf(fmaxf(sc[0], sc[1]), fmaxf(sc[2], sc[3]));
            float ex[4], sum = 0.f;
#pragma unroll
            for (int r = 0; r < 4; ++r) { ex[r] = expf(sc[r] - mx); sum += ex[r]; }
            float inv = 1.f / sum;
#pragma unroll
            for (int r = 0; r < 4; ++r) alpha[r] = ex[r] * inv;
        }

        // ---- 3 pair MLPs + scatter (p0=(m,s)->d, p1=(d,s)->m, p2=(d,m)->s) ----
        do_pair<LAYER>(0, cM, cS, sEW1, sEW2, eb1c, eb2c, alpha, nb, zb, g, t, lane, cvt0, accb);
        do_pair<LAYER>(1, cD, cS, sEW1, sEW2, eb1c, eb2c, alpha, nb, zb, g, t, lane, cvt1, accb);
        do_pair<LAYER>(2, cD, cM, sEW1, sEW2, eb1c, eb2c, alpha, nb, zb, g, t, lane, cvt2, accb);

        // ---- rotate pipeline ----
        if (hn) {
#pragma unroll
            for (int ks = 0; ks < 2; ++ks) { cD[ks] = nD[ks]; cM[ks] = nM[ks]; cS[ks] = nS[ks]; }
            cvt0 = nvt0; cvt1 = nvt1; cvt2 = nvt2;
        }
    }
}

// ---------------------------------------------------------------------------
extern "C" void kernel_launch(void* const* d_in, const int* in_sizes, int n_in,
                              void* d_out, int out_size, void* d_ws, size_t ws_size,
                              hipStream_t stream) {
    (void)in_sizes; (void)n_in; (void)out_size; (void)ws_size;
    const float* x0       = (const float*)d_in[0];
    const int* ei         = (const int*)d_in[1];
    const float* p0_Wp    = (const float*)d_in[2];
    const float* p0_aW1   = (const float*)d_in[3];
    const float* p0_ab1   = (const float*)d_in[4];
    const float* p0_aW2   = (const float*)d_in[5];
    const float* p0_ab2   = (const float*)d_in[6];
    const float* p0_eW1   = (const float*)d_in[7];
    const float* p0_eb1   = (const float*)d_in[8];
    const float* p0_eW2   = (const float*)d_in[9];
    const float* p0_eb2   = (const float*)d_in[10];
    const float* p0_theta = (const float*)d_in[11];
    const float* p0_bias  = (const float*)d_in[12];
    const float* p1_Wp    = (const float*)d_in[13];
    const float* p1_aW1   = (const float*)d_in[14];
    const float* p1_ab1   = (const float*)d_in[15];
    const float* p1_aW2   = (const float*)d_in[16];
    const float* p1_ab2   = (const float*)d_in[17];
    const float* p1_eW1   = (const float*)d_in[18];
    const float* p1_eb1   = (const float*)d_in[19];
    const float* p1_eW2   = (const float*)d_in[20];
    const float* p1_eb2   = (const float*)d_in[21];
    const float* p1_theta = (const float*)d_in[22];
    const float* p1_bias  = (const float*)d_in[23];

    // Workspace (floats; total ~36,541,440 f = 146.17 MB <= proven 146.56):
    //  [0, 15.36M):          proj1 fp32 (layer1); during layer0: proj0 fp32
    //                        [0,5.12M) + projh0 bf16 [5.12M,7.68M)
    //  [15.36M, 23.04M):     x1b  bf16 accumulator (3N x 256)
    //  [23.04M, 30.72M):     projh1 bf16 (3N x 256)
    //  [30.72M, 36.48M):     zacc bf16 accumulator (3*M1 x 64)
    //  [36.48M, ...):        compact weight images (2 x 24576) + WpT1 (65536)
    float* ws = (float*)d_ws;
    float* proj0 = ws;
    unsigned short* projh0 = (unsigned short*)(ws + 5120000);
    float* proj1 = ws;
    unsigned short* x1b    = (unsigned short*)(ws + 15360000);
    unsigned short* projh1 = (unsigned short*)(ws + 23040000);
    unsigned short* zacc   = (unsigned short*)(ws + 30720000);
    unsigned short* wt     = (unsigned short*)(ws + 36480000);
    unsigned short* wimg0 = wt;              // [aW1 12288 | eW1 8192 | eW2 4096]
    unsigned short* wimg1 = wt + 24576;
    unsigned short* wpT1  = wt + 49152;      // Wp1^T 256x256
    float* out = (float*)d_out;

    // ---- weight prep (swizzled bf16 transposes; aW1 compact 192-wide) ----
    prep_swz<<<(64 * 192 + 255) / 256, 256, 0, stream>>>(p0_aW1, wimg0,         192, 192, 7);
    prep_swz<<<(64 * 128 + 255) / 256, 256, 0, stream>>>(p0_eW1, wimg0 + 12288, 128, 128, 15);
    prep_swz<<<(64 * 64 + 255) / 256, 256, 0, stream>>>(p0_eW2, wimg0 + 20480,  64,  64,  7);
    prep_swz<<<(64 * 192 + 255) / 256, 256, 0, stream>>>(p1_aW1, wimg1,         192, 192, 7);
    prep_swz<<<(64 * 128 + 255) / 256, 256, 0, stream>>>(p1_eW1, wimg1 + 12288, 128, 128, 15);
    prep_swz<<<(64 * 64 + 255) / 256, 256, 0, stream>>>(p1_eW2, wimg1 + 20480,  64,  64,  7);
    prep_wpt<<<(256 * 256 + 255) / 256, 256, 0, stream>>>(p1_Wp, wpT1);

    // ---- layer 0 ----
    gemm_proj<64><<<N_NODES / 16, 256, 0, stream>>>(x0, p0_Wp, proj0, projh0);
    init_x1b<<<(N_NODES * 128 + 255) / 256, 256, 0, stream>>>(proj0, p0_theta, p0_bias,
                                                              (unsigned int*)x1b);
    fused_edge<0><<<PBLK, 320, 0, stream>>>(projh0, ei, wimg0, p0_ab1, p0_aW2, p0_ab2,
                                            p0_eb1, p0_eb2, x1b);
    sigmoid_x1b<<<(M1 * 128 + 255) / 256, 256, 0, stream>>>((unsigned int*)x1b);

    // ---- layer 1 ----
    gemm_mfma<<<(M1 + 63) / 64, 256, 0, stream>>>(x1b, wpT1, proj1, projh1);
    zero_zacc<<<(3 * M1 * 32 + 255) / 256, 256, 0, stream>>>((unsigned int*)zacc,
                                                             3 * M1 * 32);
    fused_edge<1><<<PBLK, 320, 0, stream>>>(projh1, ei, wimg1, p1_ab1, p1_aW2, p1_ab2,
                                            p1_eb1, p1_eb2, zacc);
    final_out<<<(M1 * 64 + 255) / 256, 256, 0, stream>>>(proj1, zacc, p1_theta,
                                                         p1_bias, out);
}

// Round 20
// 553.681 us; speedup vs baseline: 1.2323x; 1.2274x over previous
//
#include <hip/hip_runtime.h>
#include <math.h>

#define N_NODES 20000
#define E_EDGES 200000
#define M1 60000            // layer-1 node count (3*N)
#define TE 16               // edges per tile in fused kernel
#define NTILES (E_EDGES / TE)   // 12500
#define PBLK 512            // persistent blocks (2 per CU, 256 threads each)

typedef __attribute__((ext_vector_type(8))) short short8;
typedef __attribute__((ext_vector_type(4))) float f32x4;

// float -> bf16 (round-to-nearest-even), bit-level
__device__ __forceinline__ unsigned short f2bf(float f) {
    union { float f; unsigned int u; } v; v.f = f;
    unsigned int r = v.u + 0x7fffu + ((v.u >> 16) & 1u);
    return (unsigned short)(r >> 16);
}
__device__ __forceinline__ float bf2f(unsigned short u) {
    union { unsigned int u; float f; } v; v.u = ((unsigned int)u) << 16;
    return v.f;
}

// packed bf16 atomic add (2 adjacent bf16, 4B-aligned). Fire-and-forget.
__device__ __forceinline__ void atom_pk_raw(unsigned short* p, unsigned int pk) {
    asm volatile("global_atomic_pk_add_bf16 %0, %1, off" :: "v"(p), "v"(pk));
}

// ---------------------------------------------------------------------------
// Layer-0 proj GEMM: X[N,64] @ W[64,256] -> projh0 bf16, and FUSED x1b init:
// x1b[(p*N+v)*256+c] = bf16(theta0[c]*proj+bias0[c]) for p=0,1,2.
// (bit-exact fusion of the old init_x1b kernel; fp32 proj0 store dropped —
//  nothing read it once init_x1b was fused.)
// ---------------------------------------------------------------------------
__global__ __launch_bounds__(256) void gemm_proj64(const float* __restrict__ X,
                                                   const float* __restrict__ W,
                                                   unsigned short* __restrict__ Ch,
                                                   const float* __restrict__ theta,
                                                   const float* __restrict__ bias,
                                                   unsigned int* __restrict__ x1bu) {
    __shared__ float Xs[16][64];
    const int row0 = blockIdx.x * 16;
    const int tid = threadIdx.x;
    for (int i4 = tid; i4 < 16 * 64 / 4; i4 += 256) {
        int r = i4 / 16, kq = i4 - r * 16;
        ((float4*)&Xs[r][0])[kq] = ((const float4*)(X + (size_t)(row0 + r) * 64))[kq];
    }
    __syncthreads();
    const int rg = tid >> 6;
    const int j0 = (tid & 63) * 4;
    float acc[4][4];
#pragma unroll
    for (int r = 0; r < 4; ++r)
#pragma unroll
        for (int t = 0; t < 4; ++t) acc[r][t] = 0.f;
#pragma unroll 4
    for (int k = 0; k < 64; ++k) {
        float4 wq = *(const float4*)(W + (size_t)k * 256 + j0);
#pragma unroll
        for (int r = 0; r < 4; ++r) {
            float xv = Xs[rg * 4 + r][k];
            acc[r][0] = fmaf(xv, wq.x, acc[r][0]);
            acc[r][1] = fmaf(xv, wq.y, acc[r][1]);
            acc[r][2] = fmaf(xv, wq.z, acc[r][2]);
            acc[r][3] = fmaf(xv, wq.w, acc[r][3]);
        }
    }
    const float th0 = theta[j0], th1 = theta[j0 + 1], th2 = theta[j0 + 2], th3 = theta[j0 + 3];
    const float bi0 = bias[j0],  bi1 = bias[j0 + 1],  bi2 = bias[j0 + 2],  bi3 = bias[j0 + 3];
#pragma unroll
    for (int r = 0; r < 4; ++r) {
        const int row = row0 + rg * 4 + r;
        const size_t base = (size_t)row * 256 + j0;
        ushort4 h;
        h.x = f2bf(acc[r][0]); h.y = f2bf(acc[r][1]);
        h.z = f2bf(acc[r][2]); h.w = f2bf(acc[r][3]);
        *(ushort4*)(Ch + base) = h;
        float v0 = th0 * acc[r][0] + bi0;
        float v1 = th1 * acc[r][1] + bi1;
        float v2 = th2 * acc[r][2] + bi2;
        float v3 = th3 * acc[r][3] + bi3;
        unsigned int pk0 = (unsigned int)f2bf(v0) | ((unsigned int)f2bf(v1) << 16);
        unsigned int pk1 = (unsigned int)f2bf(v2) | ((unsigned int)f2bf(v3) << 16);
        const size_t xi = (size_t)row * 128 + (j0 >> 1);
        x1bu[xi] = pk0; x1bu[xi + 1] = pk1;
        x1bu[xi + (size_t)N_NODES * 128] = pk0;
        x1bu[xi + (size_t)N_NODES * 128 + 1] = pk1;
        x1bu[xi + (size_t)2 * N_NODES * 128] = pk0;
        x1bu[xi + (size_t)2 * N_NODES * 128 + 1] = pk1;
    }
}

// ---------------------------------------------------------------------------
// MFMA GEMM with FUSED sigmoid on A: C[M1,256] = sigmoid(A)[M1,256] @ B.
// A = x1b (bf16, pre-sigmoid accumulator); each A element is read exactly
// once across the grid, so inline sigmoid is exact (bit-identical to the
// old sigmoid_x1b kernel: bf16 -> f32 -> sigmoid -> bf16).
// ---------------------------------------------------------------------------
__global__ __launch_bounds__(256) void gemm_mfma(const unsigned short* __restrict__ A,
                                                 const unsigned short* __restrict__ BT,
                                                 float* __restrict__ C,
                                                 unsigned short* __restrict__ Ch) {
    const int tid = threadIdx.x;
    const int w = tid >> 6, lane = tid & 63;
    const int g = lane >> 4, t = lane & 15;
    const int rA = min(blockIdx.x * 64 + w * 16 + t, M1 - 1);
    const f32x4 z = {0.f, 0.f, 0.f, 0.f};
    f32x4 acc[16];
#pragma unroll
    for (int f = 0; f < 16; ++f) acc[f] = z;
#pragma unroll
    for (int ks = 0; ks < 8; ++ks) {
        short8 a = *(const short8*)(A + (size_t)rA * 256 + ks * 32 + g * 8);
#pragma unroll
        for (int j = 0; j < 8; ++j) {
            float s = 1.f / (1.f + expf(-bf2f((unsigned short)a[j])));
            a[j] = (short)f2bf(s);
        }
#pragma unroll
        for (int f = 0; f < 16; ++f) {
            short8 b = *(const short8*)(BT + (size_t)(16 * f + t) * 256 + ks * 32 + g * 8);
            acc[f] = __builtin_amdgcn_mfma_f32_16x16x32_bf16(a, b, acc[f], 0, 0, 0);
        }
    }
    const int rC0 = blockIdx.x * 64 + w * 16 + 4 * g;
#pragma unroll
    for (int r = 0; r < 4; ++r) {
        const int row = rC0 + r;
        if (row < M1) {
#pragma unroll
            for (int f = 0; f < 16; ++f) {
                C[(size_t)row * 256 + 16 * f + t] = acc[f][r];
                Ch[(size_t)row * 256 + 16 * f + t] = f2bf(acc[f][r]);
            }
        }
    }
}

// ---------------------------------------------------------------------------
// Weight prep (swizzled): W[K][64] fp32 -> WT[64][Wpad] bf16, transposed,
// 16B-chunk XOR swizzle: element (r, k) stored at chunk (k>>3)^(r&mask).
// ---------------------------------------------------------------------------
__global__ void prep_swz(const float* __restrict__ W, unsigned short* __restrict__ WT,
                         int Kact, int Wpad, int mask) {
    int gid = blockIdx.x * 256 + threadIdx.x;
    if (gid >= 64 * Wpad) return;
    int r = gid / Wpad, kk = gid - r * Wpad;
    int cs = kk >> 3, pos = kk & 7;
    int k = ((cs ^ (r & mask)) << 3) + pos;
    WT[gid] = (k < Kact) ? f2bf(W[k * 64 + r]) : (unsigned short)0;
}
// Wp1[256][256] -> WpT[256 out][256 k] bf16 (unswizzled, for gemm_mfma)
__global__ void prep_wpt(const float* __restrict__ W, unsigned short* __restrict__ WT) {
    int i = blockIdx.x * 256 + threadIdx.x;
    if (i >= 256 * 256) return;
    int n = i >> 8, k = i & 255;
    WT[i] = f2bf(W[k * 256 + n]);
}

__global__ void zero_zacc(unsigned int* __restrict__ z, int n) {
    int gid = blockIdx.x * 256 + threadIdx.x;
    if (gid < n) z[gid] = 0u;
}

__global__ void final_out(const float* __restrict__ proj1,
                          const unsigned short* __restrict__ zacc,
                          const float* __restrict__ theta,
                          const float* __restrict__ bias,
                          float* __restrict__ out) {
    int gid = blockIdx.x * 256 + threadIdx.x;               // over M1*64
    if (gid >= M1 * 64) return;
    int v = gid >> 6, c = gid & 63;
    float b = 0.f;
#pragma unroll
    for (int h = 0; h < 4; ++h)
        b += theta[h * 64 + c] * proj1[(size_t)v * 256 + h * 64 + c];
    float base = 0.25f * b + bias[c];
#pragma unroll
    for (int p = 0; p < 3; ++p) {
        size_t idx = (size_t)(p * M1 + v) * 64 + c;
        out[idx] = base + bf2f(zacc[idx]);
    }
}

// ---------------------------------------------------------------------------
// Pair MLP core, ALL weights from LDS (swizzled; eW2-from-global is BANNED —
// r13-vs-r15 single-variable bisect showed it corrupts results here).
// wave_barrier between nb write and cross-lane nb read (rule-18 hardening).
// ---------------------------------------------------------------------------
__device__ __forceinline__ void pair_mlp(const short8 A0[2], const short8 A1[2],
                                         const unsigned short* sEW1,
                                         const unsigned short* sEW2,
                                         const float eb1c[4],
                                         unsigned short* nb,
                                         int g, int t, f32x4 a2[4]) {
    const f32x4 z = {0.f, 0.f, 0.f, 0.f};
    f32x4 a1[4] = {z, z, z, z};
    __builtin_amdgcn_s_setprio(1);
#pragma unroll
    for (int half = 0; half < 2; ++half) {
#pragma unroll
        for (int ks = 0; ks < 2; ++ks) {
            short8 a = half ? A1[ks] : A0[ks];
#pragma unroll
            for (int f = 0; f < 4; ++f) {
                short8 b = *(const short8*)(sEW1 + (16 * f + t) * 128 +
                                            (((half * 8 + ks * 4 + g) ^ t) << 3));
                a1[f] = __builtin_amdgcn_mfma_f32_16x16x32_bf16(a, b, a1[f], 0, 0, 0);
            }
        }
    }
    __builtin_amdgcn_s_setprio(0);
#pragma unroll
    for (int f = 0; f < 4; ++f) {
        const int col = 16 * f + t;
#pragma unroll
        for (int r = 0; r < 4; ++r) {
            const int row = 4 * g + r;
            float hv = a1[f][r] + eb1c[f];
            hv = (hv >= 0.f) ? hv : 0.2f * hv;
            const int chunk = (col >> 3) ^ (row & 7);
            nb[row * 64 + chunk * 8 + (col & 7)] = f2bf(hv);
        }
    }
    __builtin_amdgcn_wave_barrier();   // cross-lane LDS handoff: write -> read
#pragma unroll
    for (int f = 0; f < 4; ++f) a2[f] = z;
    __builtin_amdgcn_s_setprio(1);
#pragma unroll
    for (int ks = 0; ks < 2; ++ks) {
        const int chunk = (ks * 4 + g) ^ (t & 7);
        short8 a = *(const short8*)(nb + t * 64 + chunk * 8);
#pragma unroll
        for (int f = 0; f < 4; ++f) {
            short8 b = *(const short8*)(sEW2 + (16 * f + t) * 64 +
                                        ((((ks * 4 + g) ^ t) & 7) << 3));
            a2[f] = __builtin_amdgcn_mfma_f32_16x16x32_bf16(a, b, a2[f], 0, 0, 0);
        }
    }
    __builtin_amdgcn_s_setprio(0);
}

// ---------------------------------------------------------------------------
// pair + scatter. Both layers stage in zb, then full-wave pk atomics over
// contiguous segments (L0: 8x256B, L1: 2x(2x128B), rotation layout).
// ---------------------------------------------------------------------------
template<int LAYER>
__device__ __forceinline__ void do_pair(int p,
                                        const short8 A0[2], const short8 A1[2],
                                        const unsigned short* sEW1,
                                        const unsigned short* sEW2,
                                        const float eb1c[4], const float eb2c[4],
                                        const float alpha[4],
                                        unsigned short* nb, unsigned short* zb,
                                        int g, int t, int lane, int vtp,
                                        unsigned short* __restrict__ accb) {
    f32x4 a2[4];
    pair_mlp(A0, A1, sEW1, sEW2, eb1c, nb, g, t, a2);
    if (LAYER == 0) {
        // stage scaled payload: value (f,r) of edge g -> zb[row=4g+r][col=16f+t]
#pragma unroll
        for (int f = 0; f < 4; ++f) {
            const int col = 16 * f + t;
#pragma unroll
            for (int r = 0; r < 4; ++r) {
                const int row = 4 * g + r;
                float val = alpha[r] * (a2[f][r] + eb2c[f]);
                const int chunk = (col >> 3) ^ (row & 7);
                zb[row * 64 + chunk * 8 + (col & 7)] = f2bf(val);
            }
        }
        __builtin_amdgcn_wave_barrier();   // cross-lane zb handoff
        int tg0 = __shfl(vtp, 0), tg1 = __shfl(vtp, 16);
        int tg2 = __shfl(vtp, 32), tg3 = __shfl(vtp, 48);
        const int tg[4] = {tg0, tg1, tg2, tg3};
        // 8 full-wave pk atomics, 256B contiguous each
#pragma unroll
        for (int e = 0; e < 4; ++e) {
            unsigned short* dst = accb + ((size_t)(p * N_NODES + tg[e])) * 256;
#pragma unroll
            for (int k = 0; k < 2; ++k) {
                const int idx = 128 * k + 2 * lane;   // col idx in [0,256)
                const int r = idx >> 6, c = idx & 63;
                const int zrow = 4 * e + r;
                const int chunk = (c >> 3) ^ (zrow & 7);
                unsigned int pk = *(const unsigned int*)(zb + zrow * 64 + chunk * 8 + (c & 7));
                atom_pk_raw(dst + idx, pk);
            }
        }
    } else {
        // head-reduce, stage u32-packed pairs with rotation layout.
        unsigned int* zbu = (unsigned int*)zb;
#pragma unroll
        for (int f = 0; f < 4; ++f) {
            float s = 0.f;
#pragma unroll
            for (int r = 0; r < 4; ++r) s += alpha[r] * (a2[f][r] + eb2c[f]);
            s *= 0.25f;
            float pv = __shfl_xor(s, 1);
            if (!(t & 1)) {
                unsigned int pk = (unsigned int)f2bf(s) | ((unsigned int)f2bf(pv) << 16);
                zbu[g * 32 + ((8 * f + (t >> 1) + 8 * g) & 31)] = pk;
            }
        }
        __builtin_amdgcn_wave_barrier();   // cross-lane zb handoff
        int tg0 = __shfl(vtp, 0), tg1 = __shfl(vtp, 16);
        int tg2 = __shfl(vtp, 32), tg3 = __shfl(vtp, 48);
        const int tg[4] = {tg0, tg1, tg2, tg3};
        // 2 full-wave pk atomics; each half-wave writes one contiguous 128B row
#pragma unroll
        for (int k = 0; k < 2; ++k) {
            const int ep = 2 * k + (lane >> 5);
            const int j = lane & 31;
            unsigned int pk = zbu[ep * 32 + ((j + 8 * ep) & 31)];
            unsigned short* dst = accb + ((size_t)(p * M1 + tg[ep])) * 64;
            atom_pk_raw(dst + 2 * j, pk);
        }
    }
}

// ---------------------------------------------------------------------------
// Fused edge kernel (MFMA, persistent, software-pipelined gather).
// r16-proven geometry: 256-thread blocks (4 waves x 4 edges), weights in LDS,
// LDS 72KB -> 2 blocks/CU = 8 waves/CU (max proven packing; >256-thread
// blocks empirically never co-schedule regardless of LDS — r17/r18/r19).
// ---------------------------------------------------------------------------
template<int LAYER>
__global__ __launch_bounds__(256) void fused_edge(const unsigned short* __restrict__ projh,
                                                  const int* __restrict__ ei,
                                                  const unsigned short* __restrict__ wimg,
                                                  const float* __restrict__ ab1,
                                                  const float* __restrict__ aW2,
                                                  const float* __restrict__ ab2,
                                                  const float* __restrict__ eb1,
                                                  const float* __restrict__ eb2,
                                                  unsigned short* __restrict__ accb) {
    __shared__ __align__(16) unsigned short sW[28672];   // aW1|eW1|eW2
    __shared__ __align__(16) unsigned short nb1[4][16 * 64];
    __shared__ __align__(16) unsigned short zb1[4][16 * 64];
    const unsigned short* sAW1 = sW;
    const unsigned short* sEW1 = sW + 16384;
    const unsigned short* sEW2 = sW + 24576;

    const int tid = threadIdx.x;
    // ---- stage weights (3584 short8, 14 per thread, coalesced) ----
    for (int i = tid; i < 28672 / 8; i += 256)
        ((short8*)sW)[i] = ((const short8*)wimg)[i];
    __syncthreads();

    const int w = tid >> 6, lane = tid & 63;
    const int g = lane >> 4, t = lane & 15;
    const int ko = g * 8;
    const int tsub = t >> 2, head = t & 3;

    float ab1c[4], aW2c[4], eb1c[4], eb2c[4];
#pragma unroll
    for (int f = 0; f < 4; ++f) {
        ab1c[f] = ab1[16 * f + t];
        aW2c[f] = aW2[16 * f + t];
        eb1c[f] = eb1[16 * f + t];
        eb2c[f] = eb2[16 * f + t];
    }
    const float b2 = ab2[0];
    unsigned short* nb = &nb1[w][0];
    unsigned short* zb = &zb1[w][0];

    // ---- prologue: gather first tile ----
    int tile = blockIdx.x;
    short8 cD[2], cM[2], cS[2];
    int cvt0, cvt1, cvt2;
    {
        const int e0 = tile * TE + w * 4;
        const int ea = e0 + tsub, ec = e0 + g;
        const int iD = ei[ea], iM = ei[E_EDGES + ea], iS = ei[2 * E_EDGES + ea];
        cvt0 = ei[ec]; cvt1 = ei[E_EDGES + ec]; cvt2 = ei[2 * E_EDGES + ec];
        const unsigned short* pD = projh + (size_t)iD * 256 + head * 64;
        const unsigned short* pM = projh + (size_t)iM * 256 + head * 64;
        const unsigned short* pS = projh + (size_t)iS * 256 + head * 64;
#pragma unroll
        for (int ks = 0; ks < 2; ++ks) {
            cD[ks] = *(const short8*)(pD + ks * 32 + ko);
            cM[ks] = *(const short8*)(pM + ks * 32 + ko);
            cS[ks] = *(const short8*)(pS + ks * 32 + ko);
        }
    }

    for (; tile < NTILES; tile += PBLK) {
        const bool hn = (tile + PBLK) < NTILES;
        // ---- prefetch next tile's edge indices ----
        int niD = 0, niM = 0, niS = 0, nvt0 = 0, nvt1 = 0, nvt2 = 0;
        if (hn) {
            const int e0n = (tile + PBLK) * TE + w * 4;
            const int ean = e0n + tsub, ecn = e0n + g;
            niD = ei[ean]; niM = ei[E_EDGES + ean]; niS = ei[2 * E_EDGES + ean];
            nvt0 = ei[ecn]; nvt1 = ei[E_EDGES + ecn]; nvt2 = ei[2 * E_EDGES + ecn];
        }

        // ---- attention MLP: H = [d|m|s] @ aW1  (K=192, padded 256) ----
        const f32x4 z = {0.f, 0.f, 0.f, 0.f};
        f32x4 acc[4] = {z, z, z, z};
        __builtin_amdgcn_s_setprio(1);
#pragma unroll
        for (int role = 0; role < 3; ++role) {
#pragma unroll
            for (int ks = 0; ks < 2; ++ks) {
                short8 a = (role == 0) ? cD[ks] : (role == 1) ? cM[ks] : cS[ks];
#pragma unroll
                for (int f = 0; f < 4; ++f) {
                    short8 b = *(const short8*)(sAW1 + (16 * f + t) * 256 +
                                                (((role * 8 + ks * 4 + g) ^ t) << 3));
                    acc[f] = __builtin_amdgcn_mfma_f32_16x16x32_bf16(a, b, acc[f], 0, 0, 0);
                }
            }
        }
        __builtin_amdgcn_s_setprio(0);

        // ---- prefetch next tile's A-fragments (hides under pairs below) ----
        short8 nD[2], nM[2], nS[2];
        if (hn) {
            const unsigned short* pD = projh + (size_t)niD * 256 + head * 64;
            const unsigned short* pM = projh + (size_t)niM * 256 + head * 64;
            const unsigned short* pS = projh + (size_t)niS * 256 + head * 64;
#pragma unroll
            for (int ks = 0; ks < 2; ++ks) {
                nD[ks] = *(const short8*)(pD + ks * 32 + ko);
                nM[ks] = *(const short8*)(pM + ks * 32 + ko);
                nS[ks] = *(const short8*)(pS + ks * 32 + ko);
            }
        }

        // ---- score epilogue: relu, @aW2, allreduce, +ab2, leaky, softmax ----
        float alpha[4];
        {
            float p_[4];
#pragma unroll
            for (int r = 0; r < 4; ++r) {
                float s = 0.f;
#pragma unroll
                for (int f = 0; f < 4; ++f) {
                    float hv = fmaxf(acc[f][r] + ab1c[f], 0.f);
                    s = fmaf(hv, aW2c[f], s);
                }
                p_[r] = s;
            }
#pragma unroll
            for (int off = 1; off < 16; off <<= 1) {
#pragma unroll
                for (int r = 0; r < 4; ++r) p_[r] += __shfl_xor(p_[r], off);
            }
            float sc[4];
#pragma unroll
            for (int r = 0; r < 4; ++r) {
                float v = p_[r] + b2;
                sc[r] = (v >= 0.f) ? v : 0.2f * v;
            }
            float mx = fmaxf(fmaxf(sc[0], sc[1]), fmaxf(sc[2], sc[3]));
            float ex[4], sum = 0.f;
#pragma unroll
            for (int r = 0; r < 4; ++r) { ex[r] = expf(sc[r] - mx); sum += ex[r]; }
            float inv = 1.f / sum;
#pragma unroll
            for (int r = 0; r < 4; ++r) alpha[r] = ex[r] * inv;
        }

        // ---- 3 pair MLPs + scatter (p0=(m,s)->d, p1=(d,s)->m, p2=(d,m)->s) ----
        do_pair<LAYER>(0, cM, cS, sEW1, sEW2, eb1c, eb2c, alpha, nb, zb, g, t, lane, cvt0, accb);
        do_pair<LAYER>(1, cD, cS, sEW1, sEW2, eb1c, eb2c, alpha, nb, zb, g, t, lane, cvt1, accb);
        do_pair<LAYER>(2, cD, cM, sEW1, sEW2, eb1c, eb2c, alpha, nb, zb, g, t, lane, cvt2, accb);

        // ---- rotate pipeline ----
        if (hn) {
#pragma unroll
            for (int ks = 0; ks < 2; ++ks) { cD[ks] = nD[ks]; cM[ks] = nM[ks]; cS[ks] = nS[ks]; }
            cvt0 = nvt0; cvt1 = nvt1; cvt2 = nvt2;
        }
    }
}

// ---------------------------------------------------------------------------
extern "C" void kernel_launch(void* const* d_in, const int* in_sizes, int n_in,
                              void* d_out, int out_size, void* d_ws, size_t ws_size,
                              hipStream_t stream) {
    (void)in_sizes; (void)n_in; (void)out_size; (void)ws_size;
    const float* x0       = (const float*)d_in[0];
    const int* ei         = (const int*)d_in[1];
    const float* p0_Wp    = (const float*)d_in[2];
    const float* p0_aW1   = (const float*)d_in[3];
    const float* p0_ab1   = (const float*)d_in[4];
    const float* p0_aW2   = (const float*)d_in[5];
    const float* p0_ab2   = (const float*)d_in[6];
    const float* p0_eW1   = (const float*)d_in[7];
    const float* p0_eb1   = (const float*)d_in[8];
    const float* p0_eW2   = (const float*)d_in[9];
    const float* p0_eb2   = (const float*)d_in[10];
    const float* p0_theta = (const float*)d_in[11];
    const float* p0_bias  = (const float*)d_in[12];
    const float* p1_Wp    = (const float*)d_in[13];
    const float* p1_aW1   = (const float*)d_in[14];
    const float* p1_ab1   = (const float*)d_in[15];
    const float* p1_aW2   = (const float*)d_in[16];
    const float* p1_ab2   = (const float*)d_in[17];
    const float* p1_eW1   = (const float*)d_in[18];
    const float* p1_eb1   = (const float*)d_in[19];
    const float* p1_eW2   = (const float*)d_in[20];
    const float* p1_eb2   = (const float*)d_in[21];
    const float* p1_theta = (const float*)d_in[22];
    const float* p1_bias  = (const float*)d_in[23];

    // Workspace (floats; total ~36,541,440 f = 146.17 MB <= proven 146.56):
    //  [0, 15.36M):          proj1 fp32 (layer1); during layer0: projh0 bf16
    //                        overlays [5.12M,7.68M) (fp32 proj0 no longer stored)
    //  [15.36M, 23.04M):     x1b  bf16 accumulator (3N x 256)
    //  [23.04M, 30.72M):     projh1 bf16 (3N x 256)
    //  [30.72M, 36.48M):     zacc bf16 accumulator (3*M1 x 64)
    //  [36.48M, ...):        swizzled bf16 weight images (2 x 28672) + WpT1 (65536)
    float* ws = (float*)d_ws;
    unsigned short* projh0 = (unsigned short*)(ws + 5120000);
    float* proj1 = ws;
    unsigned short* x1b    = (unsigned short*)(ws + 15360000);
    unsigned short* projh1 = (unsigned short*)(ws + 23040000);
    unsigned short* zacc   = (unsigned short*)(ws + 30720000);
    unsigned short* wt     = (unsigned short*)(ws + 36480000);
    unsigned short* wimg0 = wt;              // [aW1 16384 | eW1 8192 | eW2 4096]
    unsigned short* wimg1 = wt + 28672;
    unsigned short* wpT1  = wt + 57344;      // Wp1^T 256x256
    float* out = (float*)d_out;

    // ---- weight prep (swizzled bf16 transposes) ----
    prep_swz<<<(64 * 256 + 255) / 256, 256, 0, stream>>>(p0_aW1, wimg0,         192, 256, 15);
    prep_swz<<<(64 * 128 + 255) / 256, 256, 0, stream>>>(p0_eW1, wimg0 + 16384, 128, 128, 15);
    prep_swz<<<(64 * 64 + 255) / 256, 256, 0, stream>>>(p0_eW2, wimg0 + 24576,  64,  64,  7);
    prep_swz<<<(64 * 256 + 255) / 256, 256, 0, stream>>>(p1_aW1, wimg1,         192, 256, 15);
    prep_swz<<<(64 * 128 + 255) / 256, 256, 0, stream>>>(p1_eW1, wimg1 + 16384, 128, 128, 15);
    prep_swz<<<(64 * 64 + 255) / 256, 256, 0, stream>>>(p1_eW2, wimg1 + 24576,  64,  64,  7);
    prep_wpt<<<(256 * 256 + 255) / 256, 256, 0, stream>>>(p1_Wp, wpT1);

    // ---- layer 0 (proj + x1b init fused; sigmoid fused into gemm_mfma) ----
    gemm_proj64<<<N_NODES / 16, 256, 0, stream>>>(x0, p0_Wp, projh0, p0_theta, p0_bias,
                                                  (unsigned int*)x1b);
    fused_edge<0><<<PBLK, 256, 0, stream>>>(projh0, ei, wimg0, p0_ab1, p0_aW2, p0_ab2,
                                            p0_eb1, p0_eb2, x1b);

    // ---- layer 1 ----
    gemm_mfma<<<(M1 + 63) / 64, 256, 0, stream>>>(x1b, wpT1, proj1, projh1);
    zero_zacc<<<(3 * M1 * 32 + 255) / 256, 256, 0, stream>>>((unsigned int*)zacc,
                                                             3 * M1 * 32);
    fused_edge<1><<<PBLK, 256, 0, stream>>>(projh1, ei, wimg1, p1_ab1, p1_aW2, p1_ab2,
                                            p1_eb1, p1_eb2, zacc);
    final_out<<<(M1 * 64 + 255) / 256, 256, 0, stream>>>(proj1, zacc, p1_theta,
                                                         p1_bias, out);
}